// Round 5
// baseline (800.256 us; speedup 1.0000x reference)
//
#include <hip/hip_runtime.h>
#include <hip/hip_bf16.h>
#include <cstdint>
#include <cstddef>

typedef unsigned short u16;
typedef __attribute__((ext_vector_type(8))) short   short8;
typedef __attribute__((ext_vector_type(8))) __bf16  bf16x8;
typedef __attribute__((ext_vector_type(4))) float   f32x4;

#define BB       8
#define TT       1024
#define CONV_D   256
#define DMODEL   1024
#define HH       16
#define DHH      64
#define DFF      5120
#define EMB      1280
#define MROWS    8192   // B*T

__device__ __forceinline__ u16 f2bf(float f) {
    __hip_bfloat16 h = __float2bfloat16(f);
    return __builtin_bit_cast(u16, h);
}
__device__ __forceinline__ float bf2f(u16 u) {
    return __bfloat162float(__builtin_bit_cast(__hip_bfloat16, u));
}

__device__ __forceinline__ f32x4 mfma_bf16(short8 a, short8 b, f32x4 c) {
    return __builtin_amdgcn_mfma_f32_16x16x32_bf16(
        __builtin_bit_cast(bf16x8, a), __builtin_bit_cast(bf16x8, b), c, 0, 0, 0);
}

__device__ __forceinline__ void gload16(const void* g, void* l) {
    __builtin_amdgcn_global_load_lds(
        (const __attribute__((address_space(1))) void*)g,
        (__attribute__((address_space(3))) void*)l, 16, 0, 0);
}

// ---------------------------------------------------------------- prep kernels

__global__ __launch_bounds__(256) void cast_attin_kernel(
    const float* __restrict__ x, u16* __restrict__ attin)
{
    const size_t i = ((size_t)blockIdx.x * 256 + threadIdx.x) * 4;
    const size_t row = i >> 10, col = i & 1023;
    const float4 v = *reinterpret_cast<const float4*>(&x[row * EMB + CONV_D + col]);
    ushort4 o;
    o.x = f2bf(v.x); o.y = f2bf(v.y); o.z = f2bf(v.z); o.w = f2bf(v.w);
    *reinterpret_cast<ushort4*>(&attin[i]) = o;
}

// in: [K][N] f32  ->  out: [N][K] bf16   (K, N multiples of 32)
__global__ void transpose_cast_kernel(
    const float* __restrict__ in, u16* __restrict__ out, int K, int N)
{
    __shared__ __align__(16) float tile[32][33];
    const int kb = blockIdx.y * 32, nb = blockIdx.x * 32;
    const int tx = threadIdx.x, ty = threadIdx.y;
#pragma unroll
    for (int i = ty; i < 32; i += 8)
        tile[i][tx] = in[(size_t)(kb + i) * N + nb + tx];
    __syncthreads();
#pragma unroll
    for (int i = ty; i < 32; i += 8)
        out[(size_t)(nb + i) * K + kb + tx] = f2bf(tile[tx][i]);
}

// ---------------------------------------------------------------- GEMM

enum { MODE_BF16 = 0, MODE_VT = 1, MODE_BF16_RELU = 3 };

// C[M,N] = A[M,K] (bf16, row-major) x Bt[N,K] (bf16) + bias.  M mult of 128,
// N mult of 128, K mult of 32.  4 waves, 128x128 tile, BK=32.
template<int MODE>
__global__ __launch_bounds__(256) void gemm_bt_kernel(
    const u16* __restrict__ A, const u16* __restrict__ Bt,
    const float* __restrict__ bias, void* __restrict__ Cv,
    int N, int K)
{
    __shared__ __align__(16) short lA[4096];
    __shared__ __align__(16) short lB[4096];
    const int tid = threadIdx.x;
    const int l = tid & 63, w = tid >> 6;
    const int l15 = l & 15, l16 = l >> 4;
    const int m0 = blockIdx.y * 128, n0 = blockIdx.x * 128;
    const int wr = (w >> 1) * 64, wc = (w & 1) * 64;

    const int srow = tid >> 2;
    const int scol = (tid & 3) * 8;
    const u16* aS0 = A  + (size_t)(m0 + srow) * K + scol;
    const u16* aS1 = A  + (size_t)(m0 + 64 + srow) * K + scol;
    const u16* bS0 = Bt + (size_t)(n0 + srow) * K + scol;
    const u16* bS1 = Bt + (size_t)(n0 + 64 + srow) * K + scol;
    short* lA0 = &lA[w * 512];
    short* lA1 = &lA[2048 + w * 512];
    short* lB0 = &lB[w * 512];
    short* lB1 = &lB[2048 + w * 512];

    const short* aF[4];
    const short* bF[4];
#pragma unroll
    for (int mi = 0; mi < 4; ++mi) aF[mi] = &lA[(wr + mi * 16 + l15) * 32 + l16 * 8];
#pragma unroll
    for (int ni = 0; ni < 4; ++ni) bF[ni] = &lB[(wc + ni * 16 + l15) * 32 + l16 * 8];

    const f32x4 zero = {0.f, 0.f, 0.f, 0.f};
    f32x4 acc[4][4];
#pragma unroll
    for (int mi = 0; mi < 4; ++mi)
#pragma unroll
        for (int ni = 0; ni < 4; ++ni) acc[mi][ni] = zero;

    const int nk = K >> 5;
    for (int kt = 0; kt < nk; ++kt) {
        gload16(aS0, lA0); gload16(aS1, lA1);
        gload16(bS0, lB0); gload16(bS1, lB1);
        aS0 += 32; aS1 += 32; bS0 += 32; bS1 += 32;
        __syncthreads();
        short8 af[4], bf8[4];
#pragma unroll
        for (int mi = 0; mi < 4; ++mi) af[mi]  = *reinterpret_cast<const short8*>(aF[mi]);
#pragma unroll
        for (int ni = 0; ni < 4; ++ni) bf8[ni] = *reinterpret_cast<const short8*>(bF[ni]);
#pragma unroll
        for (int mi = 0; mi < 4; ++mi)
#pragma unroll
            for (int ni = 0; ni < 4; ++ni)
                acc[mi][ni] = mfma_bf16(af[mi], bf8[ni], acc[mi][ni]);
        __syncthreads();
    }

#pragma unroll
    for (int mi = 0; mi < 4; ++mi) {
#pragma unroll
        for (int ni = 0; ni < 4; ++ni) {
            const int col = n0 + wc + ni * 16 + l15;
            const float bc = bias[col];
#pragma unroll
            for (int r = 0; r < 4; ++r) {
                const int row = m0 + wr + mi * 16 + l16 * 4 + r;
                const float v = acc[mi][ni][r] + bc;
                if constexpr (MODE == MODE_BF16) {
                    ((u16*)Cv)[(size_t)row * N + col] = f2bf(v);
                } else if constexpr (MODE == MODE_BF16_RELU) {
                    ((u16*)Cv)[(size_t)row * N + col] = f2bf(fmaxf(v, 0.f));
                } else { // MODE_VT: scatter v into [B][H][DH][T]
                    const int bb = row >> 10, t = row & 1023;
                    const int hh = col >> 6,  d = col & 63;
                    ((u16*)Cv)[((size_t)((bb * HH + hh) * DHH + d)) * TT + t] = f2bf(v);
                }
            }
        }
    }
}

// ---------------------------------------------------------------- attention

// grid (T/128, B*H); 4 waves; each wave: 32 q-rows, flash over 16 k-tiles of 64
__global__ __launch_bounds__(256) void attn_kernel(
    const u16* __restrict__ qb, const u16* __restrict__ kb,
    const u16* __restrict__ vtb, const int* __restrict__ amask,
    u16* __restrict__ attb)
{
    const int tid = threadIdx.x, l = tid & 63, w = tid >> 6;
    const int l15 = l & 15, l16 = l >> 4;
    const int qt = blockIdx.x, bh = blockIdx.y;
    const int b = bh >> 4, h = bh & 15;
    __shared__ __align__(16) float sbias[1024];
    __shared__ __align__(16) short plds[4][2048];
    for (int i = tid; i < 1024; i += 256)
        sbias[i] = amask[(b << 10) + i] ? -1e9f : 0.0f;
    __syncthreads();

    const size_t rowq = (size_t)(b << 10) + (size_t)qt * 128 + w * 32;
    short8 qf[2][2];
#pragma unroll
    for (int mi = 0; mi < 2; ++mi)
#pragma unroll
        for (int ks = 0; ks < 2; ++ks)
            qf[mi][ks] = *reinterpret_cast<const short8*>(
                &qb[(rowq + mi * 16 + l15) * 1024 + h * 64 + ks * 32 + l16 * 8]);

    const f32x4 zero = {0.f, 0.f, 0.f, 0.f};
    f32x4 acc[2][4];
    float mrun[2][4], lrun[2][4];
#pragma unroll
    for (int mi = 0; mi < 2; ++mi) {
#pragma unroll
        for (int ni = 0; ni < 4; ++ni) acc[mi][ni] = zero;
#pragma unroll
        for (int r = 0; r < 4; ++r) { mrun[mi][r] = -1e30f; lrun[mi][r] = 0.f; }
    }

    const size_t kbase = (size_t)(b << 10) * 1024 + h * 64;
    const size_t vbase = (size_t)bh * 64 * 1024;

    for (int kt = 0; kt < 16; ++kt) {
        const int k0 = kt << 6;
        short8 kf[4][2];
#pragma unroll
        for (int ni = 0; ni < 4; ++ni)
#pragma unroll
            for (int ks = 0; ks < 2; ++ks)
                kf[ni][ks] = *reinterpret_cast<const short8*>(
                    &kb[kbase + (size_t)(k0 + ni * 16 + l15) * 1024 + ks * 32 + l16 * 8]);

        f32x4 s[2][4];
#pragma unroll
        for (int mi = 0; mi < 2; ++mi)
#pragma unroll
            for (int ni = 0; ni < 4; ++ni) s[mi][ni] = zero;
#pragma unroll
        for (int mi = 0; mi < 2; ++mi)
#pragma unroll
            for (int ni = 0; ni < 4; ++ni) {
                s[mi][ni] = mfma_bf16(qf[mi][0], kf[ni][0], s[mi][ni]);
                s[mi][ni] = mfma_bf16(qf[mi][1], kf[ni][1], s[mi][ni]);
            }

        float bsn[4];
#pragma unroll
        for (int ni = 0; ni < 4; ++ni) bsn[ni] = sbias[k0 + ni * 16 + l15];
#pragma unroll
        for (int mi = 0; mi < 2; ++mi)
#pragma unroll
            for (int ni = 0; ni < 4; ++ni)
#pragma unroll
                for (int r = 0; r < 4; ++r)
                    s[mi][ni][r] = s[mi][ni][r] * 0.125f + bsn[ni];

#pragma unroll
        for (int mi = 0; mi < 2; ++mi) {
#pragma unroll
            for (int r = 0; r < 4; ++r) {
                float pm = fmaxf(fmaxf(s[mi][0][r], s[mi][1][r]),
                                 fmaxf(s[mi][2][r], s[mi][3][r]));
                pm = fmaxf(pm, __shfl_xor(pm, 1));
                pm = fmaxf(pm, __shfl_xor(pm, 2));
                pm = fmaxf(pm, __shfl_xor(pm, 4));
                pm = fmaxf(pm, __shfl_xor(pm, 8));
                const float nm = fmaxf(mrun[mi][r], pm);
                const float alpha = __expf(mrun[mi][r] - nm);
                mrun[mi][r] = nm;
                float rs = 0.f;
#pragma unroll
                for (int ni = 0; ni < 4; ++ni) {
                    const float p = __expf(s[mi][ni][r] - nm);
                    s[mi][ni][r] = p;
                    rs += p;
                }
                rs += __shfl_xor(rs, 1); rs += __shfl_xor(rs, 2);
                rs += __shfl_xor(rs, 4); rs += __shfl_xor(rs, 8);
                lrun[mi][r] = lrun[mi][r] * alpha + rs;
#pragma unroll
                for (int ni = 0; ni < 4; ++ni) acc[mi][ni][r] *= alpha;
            }
        }

        // P (C/D layout) -> LDS -> A-layout fragments
#pragma unroll
        for (int mi = 0; mi < 2; ++mi)
#pragma unroll
            for (int ni = 0; ni < 4; ++ni)
#pragma unroll
                for (int r = 0; r < 4; ++r)
                    plds[w][(mi * 16 + l16 * 4 + r) * 64 + ni * 16 + l15] =
                        (short)f2bf(s[mi][ni][r]);

        short8 pf[2][2], vf[4][2];
#pragma unroll
        for (int mi = 0; mi < 2; ++mi)
#pragma unroll
            for (int ks = 0; ks < 2; ++ks)
                pf[mi][ks] = *reinterpret_cast<const short8*>(
                    &plds[w][(mi * 16 + l15) * 64 + ks * 32 + l16 * 8]);
#pragma unroll
        for (int ni = 0; ni < 4; ++ni)
#pragma unroll
            for (int ks = 0; ks < 2; ++ks)
                vf[ni][ks] = *reinterpret_cast<const short8*>(
                    &vtb[vbase + (size_t)(ni * 16 + l15) * 1024 + k0 + ks * 32 + l16 * 8]);
#pragma unroll
        for (int mi = 0; mi < 2; ++mi)
#pragma unroll
            for (int ni = 0; ni < 4; ++ni) {
                acc[mi][ni] = mfma_bf16(pf[mi][0], vf[ni][0], acc[mi][ni]);
                acc[mi][ni] = mfma_bf16(pf[mi][1], vf[ni][1], acc[mi][ni]);
            }
    }

#pragma unroll
    for (int mi = 0; mi < 2; ++mi)
#pragma unroll
        for (int ni = 0; ni < 4; ++ni)
#pragma unroll
            for (int r = 0; r < 4; ++r) {
                const float o = acc[mi][ni][r] / lrun[mi][r];
                const size_t row = rowq + mi * 16 + l16 * 4 + r;
                attb[row * 1024 + h * 64 + ni * 16 + l15] = f2bf(o);
            }
}

// ---------------------------------------------------------------- layer norms

__device__ __forceinline__ float block_sum(float v, float* red) {
    __syncthreads();
#pragma unroll
    for (int off = 32; off >= 1; off >>= 1) v += __shfl_down(v, off);
    if ((threadIdx.x & 63) == 0) red[threadIdx.x >> 6] = v;
    __syncthreads();
    return red[0] + red[1] + red[2] + red[3];
}

__global__ __launch_bounds__(256) void ln1_kernel(
    const float* __restrict__ x, const u16* __restrict__ attout,
    const float* __restrict__ conv_w, const float* __restrict__ g1,
    const float* __restrict__ beta1, const float* __restrict__ seq_mask,
    u16* __restrict__ h_bf)
{
    __shared__ float red[4];
    const int m = blockIdx.x;
    const int t = m & 1023;
    const int tid = threadIdx.x;
    const float w0 = conv_w[0], w1 = conv_w[1], w2 = conv_w[2];
    float y[5];
#pragma unroll
    for (int i = 0; i < 5; ++i) {
        const int c = i * 256 + tid;
        float v;
        if (c < CONV_D) {
            float s = x[(size_t)m * EMB + c] * w1;
            if (t > 0)    s += x[(size_t)(m - 1) * EMB + c] * w0;
            if (t < 1023) s += x[(size_t)(m + 1) * EMB + c] * w2;
            v = s;
        } else {
            v = bf2f(attout[(size_t)m * DMODEL + (c - CONV_D)]);
        }
        v += x[(size_t)m * EMB + c];
        y[i] = v;
    }
    const float mu = block_sum(y[0] + y[1] + y[2] + y[3] + y[4], red) * (1.f / EMB);
    float vs = 0.f;
#pragma unroll
    for (int i = 0; i < 5; ++i) { const float d = y[i] - mu; vs += d * d; }
    const float var = block_sum(vs, red) * (1.f / EMB);
    const float inv = rsqrtf(var + 1e-6f);
    const float sm = seq_mask[m];
#pragma unroll
    for (int i = 0; i < 5; ++i) {
        const int c = i * 256 + tid;
        float o = ((y[i] - mu) * inv * g1[c] + beta1[c]) * sm;
        h_bf[(size_t)m * EMB + c] = f2bf(o);
    }
}

__global__ __launch_bounds__(256) void ln2_kernel(
    const u16* __restrict__ ff2, const u16* __restrict__ h_bf,
    const float* __restrict__ g2, const float* __restrict__ beta2,
    const float* __restrict__ seq_mask, float* __restrict__ out)
{
    __shared__ float red[4];
    const int m = blockIdx.x;
    const int tid = threadIdx.x;
    float y[5];
#pragma unroll
    for (int i = 0; i < 5; ++i) {
        const int c = i * 256 + tid;
        y[i] = bf2f(ff2[(size_t)m * EMB + c]) + bf2f(h_bf[(size_t)m * EMB + c]);
    }
    const float mu = block_sum(y[0] + y[1] + y[2] + y[3] + y[4], red) * (1.f / EMB);
    float vs = 0.f;
#pragma unroll
    for (int i = 0; i < 5; ++i) { const float d = y[i] - mu; vs += d * d; }
    const float var = block_sum(vs, red) * (1.f / EMB);
    const float inv = rsqrtf(var + 1e-6f);
    const float sm = seq_mask[m];
#pragma unroll
    for (int i = 0; i < 5; ++i) {
        const int c = i * 256 + tid;
        const float o = ((y[i] - mu) * inv * g2[c] + beta2[c]) * sm;
        out[(size_t)m * EMB + c] = o;   // d_out is FLOAT32 (reference output dtype)
    }
}

// ---------------------------------------------------------------- launch

extern "C" void kernel_launch(void* const* d_in, const int* in_sizes, int n_in,
                              void* d_out, int out_size, void* d_ws, size_t ws_size,
                              hipStream_t stream)
{
    const float* x        = (const float*)d_in[0];
    const int*   amask    = (const int*)d_in[1];
    const float* seq_mask = (const float*)d_in[2];
    const float* conv_w   = (const float*)d_in[3];
    const float* wq = (const float*)d_in[4];  const float* bq = (const float*)d_in[5];
    const float* wk = (const float*)d_in[6];  const float* bk = (const float*)d_in[7];
    const float* wv = (const float*)d_in[8];  const float* bv = (const float*)d_in[9];
    const float* wo = (const float*)d_in[10]; const float* bo = (const float*)d_in[11];
    const float* w1 = (const float*)d_in[12]; const float* b1 = (const float*)d_in[13];
    const float* w2 = (const float*)d_in[14]; const float* b2 = (const float*)d_in[15];
    const float* g1 = (const float*)d_in[16]; const float* be1 = (const float*)d_in[17];
    const float* g2 = (const float*)d_in[18]; const float* be2 = (const float*)d_in[19];

    // ---- lifetime-aliased workspace layout (byte offsets) ----
    // [0,80M):  attin@0 | qbf@16M | kbf@32M | vtbf@48M | attout@64M
    //           attbf aliases attin@0 (attin dead after V-GEMM)
    //           midbf@0 [0,80M)  (written by ff1, all above dead by then)
    // hbf    @  83,886,080  (20 MB, live to the end)
    // ff2bf  @ 104,857,600  (20 MB; aliases wq..wo,w1t — dead by ff2)
    // wqt..wot @ 104,857,600 (+2M each), w1t @ 113,246,208, w2t @ 126,353,408
    // NEED proven safe: R2 ran with this exact layout (wrote full output).
    const size_t NEED = 139460608;
    if (ws_size < NEED) return;

    char* base = (char*)d_ws;
    u16* attin  = (u16*)(base + 0);
    u16* qbf    = (u16*)(base + 16777216);
    u16* kbf    = (u16*)(base + 33554432);
    u16* vtbf   = (u16*)(base + 50331648);
    u16* attbf  = (u16*)(base + 0);          // alias attin
    u16* attout = (u16*)(base + 67108864);
    u16* midbf  = (u16*)(base + 0);          // alias [0,80M)
    u16* hbf    = (u16*)(base + 83886080);
    u16* ff2bf  = (u16*)(base + 104857600);  // alias weight region
    u16* wqt    = (u16*)(base + 104857600);
    u16* wkt    = (u16*)(base + 106954752);
    u16* wvt    = (u16*)(base + 109051904);
    u16* wot    = (u16*)(base + 111149056);
    u16* w1t    = (u16*)(base + 113246208);
    u16* w2t    = (u16*)(base + 126353408);

    const dim3 tb(32, 8);
    cast_attin_kernel<<<8192, 256, 0, stream>>>(x, attin);
    transpose_cast_kernel<<<dim3(32, 32),  tb, 0, stream>>>(wq, wqt, 1024, 1024);
    transpose_cast_kernel<<<dim3(32, 32),  tb, 0, stream>>>(wk, wkt, 1024, 1024);
    transpose_cast_kernel<<<dim3(32, 32),  tb, 0, stream>>>(wv, wvt, 1024, 1024);
    transpose_cast_kernel<<<dim3(32, 32),  tb, 0, stream>>>(wo, wot, 1024, 1024);
    transpose_cast_kernel<<<dim3(160, 40), tb, 0, stream>>>(w1, w1t, 1280, 5120);
    transpose_cast_kernel<<<dim3(40, 160), tb, 0, stream>>>(w2, w2t, 5120, 1280);

    gemm_bt_kernel<MODE_BF16><<<dim3(8, 64), 256, 0, stream>>>(attin, wqt, bq, qbf, 1024, 1024);
    gemm_bt_kernel<MODE_BF16><<<dim3(8, 64), 256, 0, stream>>>(attin, wkt, bk, kbf, 1024, 1024);
    gemm_bt_kernel<MODE_VT>  <<<dim3(8, 64), 256, 0, stream>>>(attin, wvt, bv, vtbf, 1024, 1024);
    attn_kernel<<<dim3(8, 128), 256, 0, stream>>>(qbf, kbf, vtbf, amask, attbf);
    gemm_bt_kernel<MODE_BF16><<<dim3(8, 64), 256, 0, stream>>>(attbf, wot, bo, attout, 1024, 1024);
    ln1_kernel<<<8192, 256, 0, stream>>>(x, attout, conv_w, g1, be1, seq_mask, hbf);
    gemm_bt_kernel<MODE_BF16_RELU><<<dim3(40, 64), 256, 0, stream>>>(hbf, w1t, b1, midbf, 5120, 1280);
    gemm_bt_kernel<MODE_BF16><<<dim3(10, 64), 256, 0, stream>>>(midbf, w2t, b2, ff2bf, 1280, 5120);
    ln2_kernel<<<8192, 256, 0, stream>>>(ff2bf, hbf, g2, be2, seq_mask, (float*)d_out);
}